// Round 13
// baseline (403.890 us; speedup 1.0000x reference)
//
#include <hip/hip_runtime.h>
#include <hip/hip_cooperative_groups.h>
#include <math.h>

namespace cg = cooperative_groups;

#define NPGN 61
#define NGRAPH 128
#define NNODES (NPGN*NGRAPH)   // 7808
#define EPG 3660               // 61*60 edges per graph

typedef float float4v __attribute__((ext_vector_type(4)));
typedef short bf16x8 __attribute__((ext_vector_type(8)));
typedef unsigned short u16;

__device__ __forceinline__ u16 f2bf(float v){
  union { float f; unsigned u; } x; x.f = v;
  unsigned r = (x.u + 0x7FFFu + ((x.u >> 16) & 1u)) >> 16;
  return (u16)r;
}
__device__ __forceinline__ float bf2f(unsigned u){
  union { unsigned u; float f; } x; x.u = u << 16;
  return x.f;
}

struct GArgs {
  const float *x, *ef;
  const float *cw0, *cb0, *cw1, *cb1, *cw2, *cb2;
  const float *bn1g, *bn1b;
  const float *gw0, *gb0, *gw1, *gb1, *gw2, *gb2;
  const float *bn2g, *bn2b;
  const float *lw0, *lb0, *lw1, *lb1, *lw2, *lb2;
  const float *eww, *ewb;
  float *out;
  float *w0t; u16 *w1b, *w2b, *gwt0, *gwt1, *gwt2, *lw0t;
  float *h0; u16 *hB;
  float *stat1p, *y0pre, *stat2p;
};

#define A0T_STR 72   // u16 units (144 B)
#define C1_STR 40    // u16 units (80 B)
#define EW_STR 72
#define HS_STR 136
#define HWT_STR 72
#define AS_STR 136
#define CONV_SLICE 6112   // bytes per wave: a0t 5184 + a1k 416 + hstat 512

__global__ __launch_bounds__(512, 1) void k_mega(GArgs a){
  cg::grid_group grid = cg::this_grid();
  __shared__ __align__(16) unsigned char smem[49152];
  const int tid = threadIdx.x, bid = blockIdx.x;

  // =============== P0: weight prep + accumulator zeroing (barrier-free) =====
  {
    for (int idx = bid*512 + tid; idx < 1094080; idx += 131072){
      if (idx < 20480){
        int f = idx/320, r = idx - f*320, kk = r >> 6, c = r & 63;
        a.w1b[idx] = f2bf(a.cw1[f*320 + c*5 + kk]);
      } else if (idx < 32768){
        int j = idx - 20480; a.w2b[j] = f2bf(a.cw2[j]);
      } else if (idx < 40960){
        int j = idx - 32768; int jj = j >> 6, k = j & 63;
        a.gwt0[j] = f2bf(a.gw0[k*128 + jj]);
      } else if (idx < 57344){
        int j = idx - 40960; int jj = j >> 7, k = j & 127;
        a.gwt1[j] = f2bf(a.gw1[k*128 + jj]);
      } else if (idx < 73728){
        int j = idx - 57344; int jj = j >> 7, k = j & 127;
        a.gwt2[j] = f2bf(a.gw2[k*128 + jj]);
      } else if (idx < 74176){
        int j = idx - 73728; int k = j >> 6, f = j & 63;
        a.w0t[j] = a.cw0[f*7 + k];
      } else if (idx < 94656){
        int j = idx - 74176;
        if (j < 4096) a.stat1p[j] = 0.f;
        else          a.y0pre[j - 4096] = 0.f;
      } else {
        int j = idx - 94656;           // 0 .. 999423 : lw0t[i][o][k] bf16
        int i = j >> 14, rem = j & 16383, o = rem >> 7, k = rem & 127;
        a.lw0t[j] = f2bf(a.lw0[((size_t)i*128 + k)*128 + o]);
      }
    }
  }
  grid.sync();

  // =============== P1: conv stack (8 waves/block, 4 iters) ==================
  {
    const int w = tid >> 6, lane = tid & 63;
    const int q = lane >> 4, r16 = lane & 15;
    u16* a0t = (u16*)(smem + w*CONV_SLICE);
    u16* a1k = (u16*)(smem + w*CONV_SLICE + 5184);
    float* hst = (float*)(smem + w*CONV_SLICE + 5600);
    float w0r[7];
    #pragma unroll
    for (int k = 0; k < 7; k++) w0r[k] = a.w0t[k*64 + lane];
    float b0f = a.cb0[lane];

    #pragma unroll 1
    for (int iter = 0; iter < 4; iter++){
      int n = iter*2048 + bid*8 + w;
      bool act = n < NNODES;
      if (act){
        // zero halo rows (c1 overlay dirties them each iter)
        #pragma unroll
        for (int rp = 0; rp < 36; rp++)
          if (rp < 2 || rp >= 24) a0t[rp*A0T_STR + lane] = 0;

        const float* xrow = a.x + (size_t)__builtin_amdgcn_readfirstlane(n)*160;

        // conv0 (K=7) + relu + maxpool7 : 160 -> 154 -> 22 ; lane = channel
        #pragma unroll 2
        for (int qp = 0; qp < 11; qp++){
          float win[20];
          #pragma unroll
          for (int j = 0; j < 20; j++) win[j] = xrow[14*qp + j];
          float m0, m1;
          #pragma unroll
          for (int r = 0; r < 7; r++){
            float s = w0r[0]*win[r];
            #pragma unroll
            for (int k = 1; k < 7; k++) s += w0r[k]*win[r+k];
            m0 = r ? fmaxf(m0, s) : s;
          }
          #pragma unroll
          for (int r = 7; r < 14; r++){
            float s = w0r[0]*win[r];
            #pragma unroll
            for (int k = 1; k < 7; k++) s += w0r[k]*win[r+k];
            m1 = (r > 7) ? fmaxf(m1, s) : s;
          }
          a0t[(2 + 2*qp)*A0T_STR + lane] = f2bf(fmaxf(m0 + b0f, 0.f));
          a0t[(3 + 2*qp)*A0T_STR + lane] = f2bf(fmaxf(m1 + b0f, 0.f));
        }

        // conv1 MFMA: C[64f][22p] = W[64f][320] * B[320][22p]
        float4v acc[4][2];
        #pragma unroll
        for (int mt = 0; mt < 4; mt++)
          #pragma unroll
          for (int nt = 0; nt < 2; nt++)
            acc[mt][nt] = (float4v){0.f,0.f,0.f,0.f};
        #pragma unroll 1
        for (int ks = 0; ks < 10; ks++){
          int kk = ks >> 1;
          int cbase = (ks & 1)*32 + q*8;
          bf16x8 af[4];
          #pragma unroll
          for (int mt = 0; mt < 4; mt++)
            af[mt] = *(const bf16x8*)(a.w1b + (16*mt + r16)*320 + ks*32 + q*8);
          bf16x8 bv[2];
          #pragma unroll
          for (int nt = 0; nt < 2; nt++)
            bv[nt] = *(const bf16x8*)(a0t + (r16 + 16*nt + kk)*A0T_STR + cbase);
          #pragma unroll
          for (int mt = 0; mt < 4; mt++)
            #pragma unroll
            for (int nt = 0; nt < 2; nt++)
              acc[mt][nt] = __builtin_amdgcn_mfma_f32_16x16x32_bf16(af[mt], bv[nt], acc[mt][nt], 0, 0, 0);
        }

        // bias + relu -> c1 (overlays a0t; same-wave DS in-order)
        u16* c1 = a0t;
        #pragma unroll
        for (int mt = 0; mt < 4; mt++){
          float4 bb = *(const float4*)(a.cb1 + 16*mt + 4*q);
          #pragma unroll
          for (int reg = 0; reg < 4; reg++){
            int m = 16*mt + q*4 + reg;
            float bv_ = ((const float*)&bb)[reg];
            c1[m*C1_STR + r16] = f2bf(fmaxf(acc[mt][0][reg] + bv_, 0.f));
            if (r16 <= 4)
              c1[m*C1_STR + 16 + r16] = f2bf(fmaxf(acc[mt][1][reg] + bv_, 0.f));
          }
        }

        // maxpool7 (21 -> 3) -> a1k[c*3+t]
        {
          bf16x8 f0 = *(const bf16x8*)(c1 + lane*C1_STR);
          bf16x8 f1 = *(const bf16x8*)(c1 + lane*C1_STR + 8);
          bf16x8 f2 = *(const bf16x8*)(c1 + lane*C1_STR + 16);
          float v[24];
          #pragma unroll
          for (int j = 0; j < 8; j++){
            v[j]    = bf2f((u16)f0[j]);
            v[8+j]  = bf2f((u16)f1[j]);
            v[16+j] = bf2f((u16)f2[j]);
          }
          #pragma unroll
          for (int t = 0; t < 3; t++){
            float m = v[t*7];
            #pragma unroll
            for (int r = 1; r < 7; r++) m = fmaxf(m, v[t*7+r]);
            a1k[lane*3 + t] = f2bf(m);
          }
        }

        // conv2 via MFMA: C[f] = W2[64f][192k] * a1[192k]
        float4v acc2[4];
        #pragma unroll
        for (int mt = 0; mt < 4; mt++) acc2[mt] = (float4v){0.f,0.f,0.f,0.f};
        #pragma unroll
        for (int ks = 0; ks < 6; ks++){
          bf16x8 bs = *(const bf16x8*)(a1k + ks*32 + q*8);
          #pragma unroll
          for (int mt = 0; mt < 4; mt++){
            bf16x8 af = *(const bf16x8*)(a.w2b + (16*mt + r16)*192 + ks*32 + q*8);
            acc2[mt] = __builtin_amdgcn_mfma_f32_16x16x32_bf16(af, bs, acc2[mt], 0, 0, 0);
          }
        }
        if (r16 == 0){
          #pragma unroll
          for (int mt = 0; mt < 4; mt++)
            #pragma unroll
            for (int reg = 0; reg < 4; reg++){
              int f = 16*mt + 4*q + reg;
              float v = acc2[mt][reg] + a.cb2[f];
              a.h0[(size_t)n*64 + f] = v;
              hst[f] = v;
              hst[64 + f] = v*v;
            }
        }
      } else {
        hst[lane] = 0.f; hst[64 + lane] = 0.f;
      }
      __syncthreads();
      if (tid < 128){
        float s = 0.f;
        #pragma unroll
        for (int w8 = 0; w8 < 8; w8++)
          s += *(const float*)(smem + w8*CONV_SLICE + 5600 + tid*4);
        atomicAdd(&a.stat1p[(bid & 31)*128 + tid], s);
      }
      __syncthreads();
    }
  }
  grid.sync();

  // =============== P2: GNN (blocks 0..127, one graph each) ==================
  if (bid < NGRAPH){
    const int g = bid;
    const int w = tid >> 6, lane = tid & 63, q = lane >> 4, r16 = lane & 15;
    const int dt = w & 3, jh = w >> 2;
    u16* hs   = (u16*)(smem);
    u16* hwT  = (u16*)(smem + 17408);
    u16* ewl  = (u16*)(smem + 35840);
    float* bsc = (float*)(smem + 45056);
    float* bsh = (float*)(smem + 45312);
    float* st2 = (float*)(smem + 45568);

    bf16x8 af0[2], af1[4], af2[4];
    #pragma unroll
    for (int ks = 0; ks < 2; ks++)
      af0[ks] = *(const bf16x8*)(a.gwt0 + (16*w + r16)*64 + ks*32 + q*8);
    #pragma unroll
    for (int ks = 0; ks < 4; ks++)
      af1[ks] = *(const bf16x8*)(a.gwt1 + (16*w + r16)*128 + ks*32 + q*8);
    #pragma unroll
    for (int ks = 0; ks < 4; ks++)
      af2[ks] = *(const bf16x8*)(a.gwt2 + (16*w + r16)*128 + ks*32 + q*8);
    float4 b40 = *(const float4*)(a.gb0 + 16*w + 4*q);
    float4 b41 = *(const float4*)(a.gb1 + 16*w + 4*q);
    float4 b42 = *(const float4*)(a.gb2 + 16*w + 4*q);

    if (tid < 64){
      float s = 0.f, s2 = 0.f;
      #pragma unroll
      for (int r = 0; r < 32; r++){
        s  += a.stat1p[r*128 + tid];
        s2 += a.stat1p[r*128 + 64 + tid];
      }
      float m = s*(1.f/NNODES), v = s2*(1.f/NNODES) - m*m;
      float sc = rsqrtf(v + 1e-5f)*a.bn1g[tid];
      bsc[tid] = sc; bsh[tid] = a.bn1b[tid] - m*sc;
    }
    if (tid < 256) st2[tid] = 0.f;
    {
      unsigned* td = (unsigned*)ewl;
      for (int idx = tid; idx < 64*EW_STR/2; idx += 512) td[idx] = 0;
    }
    {
      unsigned* hsd = (unsigned*)hs;
      for (int idx = tid; idx < 3*(HS_STR/2); idx += 512){
        int rr = 61 + idx/(HS_STR/2), cc = idx%(HS_STR/2);
        hsd[rr*(HS_STR/2) + cc] = 0;
      }
    }
    __syncthreads();

    {
      float v0 = a.eww[0], v1 = a.eww[1], v2 = a.eww[2], bb = a.ewb[0];
      const float* efg = a.ef + (size_t)g*EPG*3;
      for (int idx = tid; idx < EPG; idx += 512){
        const float* p = efg + idx*3;
        float v = tanhf(p[0]*v0 + p[1]*v1 + p[2]*v2 + bb);
        int s = idx/60, r = idx - s*60;
        int d = r + (r >= s ? 1 : 0);
        ewl[d*EW_STR + s] = f2bf(v);
        a.out[512 + (size_t)idx*128 + g] = v;
      }
    }
    {
      unsigned* hsd = (unsigned*)hs;
      for (int idx = tid; idx < 61*32; idx += 512){
        int i = idx >> 5, kw = idx & 31;
        float2 hv = *(const float2*)(a.h0 + ((size_t)g*61 + i)*64 + kw*2);
        int k0 = kw*2;
        float va = hv.x*bsc[k0] + bsh[k0];
        float vb = hv.y*bsc[k0+1] + bsh[k0+1];
        hsd[i*(HS_STR/2) + kw] = (unsigned)f2bf(va) | ((unsigned)f2bf(vb) << 16);
      }
    }
    __syncthreads();
    bf16x8 ewf[2];
    #pragma unroll
    for (int ks = 0; ks < 2; ks++)
      ewf[ks] = *(const bf16x8*)(ewl + (16*dt + r16)*EW_STR + ks*32 + q*8);

    // layer 0
    #pragma unroll
    for (int nt = 0; nt < 4; nt++){
      float4v acc = {b40.x, b40.y, b40.z, b40.w};
      #pragma unroll
      for (int ks = 0; ks < 2; ks++){
        bf16x8 bv = *(const bf16x8*)(hs + (nt*16 + r16)*HS_STR + ks*32 + q*8);
        acc = __builtin_amdgcn_mfma_f32_16x16x32_bf16(af0[ks], bv, acc, 0, 0, 0);
      }
      #pragma unroll
      for (int r = 0; r < 4; r++)
        hwT[(16*w + 4*q + r)*HWT_STR + nt*16 + r16] = f2bf(acc[r]);
    }
    __syncthreads();
    #pragma unroll
    for (int nt = 0; nt < 4; nt++){
      int j = (jh*4 + nt)*16;
      float4v acc = {0.f,0.f,0.f,0.f};
      #pragma unroll
      for (int ks = 0; ks < 2; ks++){
        bf16x8 bv = *(const bf16x8*)(hwT + (j + r16)*HWT_STR + ks*32 + q*8);
        acc = __builtin_amdgcn_mfma_f32_16x16x32_bf16(ewf[ks], bv, acc, 0, 0, 0);
      }
      #pragma unroll
      for (int r = 0; r < 4; r++){
        int d = 16*dt + 4*q + r;
        hs[d*HS_STR + j + r16] = f2bf(fmaxf(acc[r], 0.f));
      }
    }
    __syncthreads();

    // layer 1
    #pragma unroll
    for (int nt = 0; nt < 4; nt++){
      float4v acc = {b41.x, b41.y, b41.z, b41.w};
      #pragma unroll
      for (int ks = 0; ks < 4; ks++){
        bf16x8 bv = *(const bf16x8*)(hs + (nt*16 + r16)*HS_STR + ks*32 + q*8);
        acc = __builtin_amdgcn_mfma_f32_16x16x32_bf16(af1[ks], bv, acc, 0, 0, 0);
      }
      #pragma unroll
      for (int r = 0; r < 4; r++)
        hwT[(16*w + 4*q + r)*HWT_STR + nt*16 + r16] = f2bf(acc[r]);
    }
    __syncthreads();
    #pragma unroll
    for (int nt = 0; nt < 4; nt++){
      int j = (jh*4 + nt)*16;
      float4v acc = {0.f,0.f,0.f,0.f};
      #pragma unroll
      for (int ks = 0; ks < 2; ks++){
        bf16x8 bv = *(const bf16x8*)(hwT + (j + r16)*HWT_STR + ks*32 + q*8);
        acc = __builtin_amdgcn_mfma_f32_16x16x32_bf16(ewf[ks], bv, acc, 0, 0, 0);
      }
      #pragma unroll
      for (int r = 0; r < 4; r++){
        int d = 16*dt + 4*q + r;
        hs[d*HS_STR + j + r16] = f2bf(fmaxf(acc[r], 0.f));
      }
    }
    __syncthreads();

    // layer 2 (+ bn2 partial tail)
    #pragma unroll
    for (int nt = 0; nt < 4; nt++){
      float4v acc = {b42.x, b42.y, b42.z, b42.w};
      #pragma unroll
      for (int ks = 0; ks < 4; ks++){
        bf16x8 bv = *(const bf16x8*)(hs + (nt*16 + r16)*HS_STR + ks*32 + q*8);
        acc = __builtin_amdgcn_mfma_f32_16x16x32_bf16(af2[ks], bv, acc, 0, 0, 0);
      }
      #pragma unroll
      for (int r = 0; r < 4; r++)
        hwT[(16*w + 4*q + r)*HWT_STR + nt*16 + r16] = f2bf(acc[r]);
    }
    __syncthreads();
    #pragma unroll
    for (int nt = 0; nt < 4; nt++){
      int j = (jh*4 + nt)*16;
      float4v acc = {0.f,0.f,0.f,0.f};
      #pragma unroll
      for (int ks = 0; ks < 2; ks++){
        bf16x8 bv = *(const bf16x8*)(hwT + (j + r16)*HWT_STR + ks*32 + q*8);
        acc = __builtin_amdgcn_mfma_f32_16x16x32_bf16(ewf[ks], bv, acc, 0, 0, 0);
      }
      float cs = 0.f, cq = 0.f;
      #pragma unroll
      for (int r = 0; r < 4; r++){
        int d = 16*dt + 4*q + r;
        if (d < 61){
          float v = acc[r];
          a.hB[((size_t)g*61 + d)*128 + j + r16] = f2bf(v);
          cs += v; cq += v*v;
        }
      }
      int col = j + r16;
      atomicAdd(&st2[col], cs);
      atomicAdd(&st2[128 + col], cq);
    }
    __syncthreads();
    if (tid < 256) a.stat2p[(size_t)tid*128 + g] = st2[tid];
  }
  grid.sync();

  // =============== P3: lin0 MFMA (512 half-teams over 244 tasks) ============
  {
    const int team = tid >> 8, ltid = tid & 255;
    int task = bid*2 + team;                  // 0..511
    bool act = task < NPGN*4;
    int bi = act ? task : 0;
    int i = bi >> 2, sub = bi & 3, oh = sub & 1, gh = sub >> 1;
    const int w = ltid >> 6, lane = ltid & 63, q = lane >> 4, r16 = lane & 15;
    u16* As = (u16*)(smem + team*18432);
    float* sc2 = (float*)(smem + team*18432 + 17408);
    float* sh2 = (float*)(smem + team*18432 + 17920);
    if (ltid < 128){
      float4v sa = {0,0,0,0}, sb = {0,0,0,0};
      #pragma unroll
      for (int r = 0; r < 32; r++){
        sa += *(const float4v*)(a.stat2p + (size_t)ltid*128 + r*4);
        sb += *(const float4v*)(a.stat2p + (size_t)(128 + ltid)*128 + r*4);
      }
      float s = sa[0]+sa[1]+sa[2]+sa[3], s2 = sb[0]+sb[1]+sb[2]+sb[3];
      float m = s*(1.f/NNODES), v = s2*(1.f/NNODES) - m*m;
      float sc = rsqrtf(v + 1e-5f)*a.bn2g[ltid];
      sc2[ltid] = sc; sh2[ltid] = a.bn2b[ltid] - m*sc;
    }
    __syncthreads();
    {
      const unsigned* hbd = (const unsigned*)a.hB;
      unsigned* asd = (unsigned*)As;
      for (int idx = ltid; idx < 4096; idx += 256){
        int gg = gh*64 + (idx >> 6), kw = idx & 63;
        unsigned pv = hbd[((size_t)gg*61 + i)*64 + kw];
        int k0 = kw*2;
        float va = bf2f(pv & 0xffffu)*sc2[k0] + sh2[k0];
        float vb = bf2f(pv >> 16)*sc2[k0+1] + sh2[k0+1];
        asd[(idx >> 6)*(AS_STR/2) + kw] = (unsigned)f2bf(va) | ((unsigned)f2bf(vb) << 16);
      }
    }
    __syncthreads();
    const u16* wbase = a.lw0t + ((size_t)i*128 + oh*64)*128;
    bf16x8 af[4];
    #pragma unroll
    for (int ks = 0; ks < 4; ks++)
      af[ks] = *(const bf16x8*)(As + (16*w + r16)*AS_STR + ks*32 + q*8);
    #pragma unroll
    for (int nt = 0; nt < 4; nt++){
      float4v acc = {0.f,0.f,0.f,0.f};
      #pragma unroll
      for (int ks = 0; ks < 4; ks++){
        bf16x8 bv = *(const bf16x8*)(wbase + (size_t)(nt*16 + r16)*128 + ks*32 + q*8);
        acc = __builtin_amdgcn_mfma_f32_16x16x32_bf16(af[ks], bv, acc, 0, 0, 0);
      }
      if (act){
        #pragma unroll
        for (int r = 0; r < 4; r++){
          int g = gh*64 + 16*w + 4*q + r;
          atomicAdd(&a.y0pre[(size_t)g*128 + oh*64 + nt*16 + r16], acc[r]);
        }
      }
    }
  }
  grid.sync();

  // =============== P4: epilogue MLP (32 blocks x 4 teams of 128) ============
  if (bid < 32){
    const int team = tid >> 7, o = tid & 127;
    const int g = bid*4 + team;
    float* y0  = (float*)(smem + team*1536);
    float* y1  = y0 + 128;
    float* red = y0 + 256;
    y0[o] = fmaxf(a.y0pre[(size_t)g*128 + o] + a.lb0[o], 0.f);
    __syncthreads();
    float acc = a.lb1[o];
    #pragma unroll 8
    for (int k = 0; k < 128; k++) acc += y0[k]*a.lw1[k*128 + o];
    y1[o] = fmaxf(acc, 0.f);
    __syncthreads();
    int c = o & 3, kb = o >> 2;
    float a2 = 0.f;
    #pragma unroll
    for (int j = 0; j < 4; j++){
      int k = kb + 32*j;
      a2 += y1[k]*a.lw2[k*4 + c];
    }
    red[o] = a2;
    __syncthreads();
    #pragma unroll
    for (int off = 64; off >= 4; off >>= 1){
      if (o < off) red[o] += red[o + off];
      __syncthreads();
    }
    if (o == 0){
      float v0 = red[0]+a.lb2[0], v1 = red[1]+a.lb2[1];
      float v2 = red[2]+a.lb2[2], v3 = red[3]+a.lb2[3];
      float m = fmaxf(fmaxf(v0,v1), fmaxf(v2,v3));
      float lse = m + logf(expf(v0-m)+expf(v1-m)+expf(v2-m)+expf(v3-m));
      a.out[g*4+0]=v0-lse; a.out[g*4+1]=v1-lse; a.out[g*4+2]=v2-lse; a.out[g*4+3]=v3-lse;
    }
  }
}

extern "C" void kernel_launch(void* const* d_in, const int* in_sizes, int n_in,
                              void* d_out, int out_size, void* d_ws, size_t ws_size,
                              hipStream_t stream){
  GArgs a;
  a.x    = (const float*)d_in[0];
  a.ef   = (const float*)d_in[3];
  a.cw0  = (const float*)d_in[4];
  a.cb0  = (const float*)d_in[5];
  a.cw1  = (const float*)d_in[6];
  a.cb1  = (const float*)d_in[7];
  a.cw2  = (const float*)d_in[8];
  a.cb2  = (const float*)d_in[9];
  a.bn1g = (const float*)d_in[10];
  a.bn1b = (const float*)d_in[11];
  a.gw0  = (const float*)d_in[12];
  a.gb0  = (const float*)d_in[13];
  a.gw1  = (const float*)d_in[14];
  a.gb1  = (const float*)d_in[15];
  a.gw2  = (const float*)d_in[16];
  a.gb2  = (const float*)d_in[17];
  a.bn2g = (const float*)d_in[18];
  a.bn2b = (const float*)d_in[19];
  a.lw0  = (const float*)d_in[20];
  a.lb0  = (const float*)d_in[21];
  a.lw1  = (const float*)d_in[22];
  a.lb1  = (const float*)d_in[23];
  a.lw2  = (const float*)d_in[24];
  a.lb2  = (const float*)d_in[25];
  a.eww  = (const float*)d_in[26];
  a.ewb  = (const float*)d_in[27];
  a.out  = (float*)d_out;

  float* ws = (float*)d_ws;
  float* w1s  = ws;               // 10240 f
  float* w2s  = w1s + 10240;      // 6144 f
  float* w0t  = w2s + 6144;       // 448 f
  float* gws0 = w0t + 448;        // 4096 f
  float* gws1 = gws0 + 4096;      // 8192 f
  float* gws2 = gws1 + 8192;      // 8192 f
  float* h0   = gws2 + 8192;      // 499712 f
  float* hBs  = h0 + 499712;      // 499712 f (7808*128 u16)
  float* lw0s = hBs + 499712;     // 499712 f (61*128*128 u16)
  float* accs = lw0s + 499712;    // stat1p(4096) | y0pre(16384) | stat2p(32768)

  a.w0t  = w0t;
  a.w1b  = (u16*)w1s;
  a.w2b  = (u16*)w2s;
  a.gwt0 = (u16*)gws0;
  a.gwt1 = (u16*)gws1;
  a.gwt2 = (u16*)gws2;
  a.h0   = h0;
  a.hB   = (u16*)hBs;
  a.lw0t = (u16*)lw0s;
  a.stat1p = accs;
  a.y0pre  = accs + 4096;
  a.stat2p = accs + 20480;

  void* kargs[] = { (void*)&a };
  hipLaunchCooperativeKernel((const void*)k_mega, dim3(256), dim3(512),
                             kargs, 0, stream);
}

// Round 14
// 235.319 us; speedup vs baseline: 1.7164x; 1.7164x over previous
//
#include <hip/hip_runtime.h>
#include <math.h>

#define NPGN 61
#define NGRAPH 128
#define NNODES (NPGN*NGRAPH)   // 7808
#define EPG 3660               // 61*60 edges per graph

typedef float float4v __attribute__((ext_vector_type(4)));
typedef short bf16x8 __attribute__((ext_vector_type(8)));
typedef unsigned short u16;

__device__ __forceinline__ u16 f2bf(float v){
  union { float f; unsigned u; } x; x.f = v;
  unsigned r = (x.u + 0x7FFFu + ((x.u >> 16) & 1u)) >> 16;
  return (u16)r;
}
__device__ __forceinline__ float bf2f(unsigned u){
  union { unsigned u; float f; } x; x.u = u << 16;
  return x.f;
}

// ---------------- fused prep: weight re-layouts + lw0 transpose -------------
__global__ __launch_bounds__(256) void k_prep(const float* __restrict__ w0,
    const float* __restrict__ w1, const float* __restrict__ w2,
    const float* __restrict__ gw0, const float* __restrict__ gw1, const float* __restrict__ gw2,
    const float* __restrict__ lw0,
    float* __restrict__ w0t, u16* __restrict__ w1b, u16* __restrict__ w2b,
    u16* __restrict__ gwt0, u16* __restrict__ gwt1, u16* __restrict__ gwt2,
    u16* __restrict__ lw0t){
  __shared__ __align__(16) u16 tile[32*132];
  int b = blockIdx.x, tid = threadIdx.x;
  if (b < 290){
    int idx = b*256 + tid;
    if (idx < 20480){
      int f = idx / 320, r = idx - f*320;
      int kk = r >> 6, c = r & 63;
      w1b[idx] = f2bf(w1[f*320 + c*5 + kk]);
    } else if (idx < 32768){
      int j = idx - 20480; w2b[j] = f2bf(w2[j]);
    } else if (idx < 40960){
      int j = idx - 32768; int jj = j >> 6, k = j & 63; gwt0[j] = f2bf(gw0[k*128 + jj]);
    } else if (idx < 57344){
      int j = idx - 40960; int jj = j >> 7, k = j & 127; gwt1[j] = f2bf(gw1[k*128 + jj]);
    } else if (idx < 73728){
      int j = idx - 57344; int jj = j >> 7, k = j & 127; gwt2[j] = f2bf(gw2[k*128 + jj]);
    } else if (idx < 74176){
      int j = idx - 73728; int k = j >> 6, f = j & 63; w0t[j] = w0[f*7 + k];
    }
  } else {
    int bb = b - 290;
    int i = bb >> 2, oq = bb & 3;      // o-chunk of 32
    for (int idx = tid; idx < 4096; idx += 256){
      int k = idx >> 5, ol = idx & 31;
      tile[ol*132 + k] = f2bf(lw0[((size_t)i*128 + k)*128 + oq*32 + ol]);
    }
    __syncthreads();
    unsigned* dst = (unsigned*)lw0t;
    for (int idx = tid; idx < 2048; idx += 256){
      int ol = idx >> 6, kw = idx & 63;
      unsigned v = (unsigned)tile[ol*132 + 2*kw] | ((unsigned)tile[ol*132 + 2*kw + 1] << 16);
      dst[((size_t)i*128 + oq*32 + ol)*64 + kw] = v;
    }
  }
}

// ---------------- conv stack: 2 nodes/block, 2 waves/node -------------------
// Each serial stage split across the node's 2 waves (conv0 positions, conv1/2 f-halves)
#define A0T_STR 72   // u16 units (144 B)
#define C1_STR 40    // u16 units (80 B)
__global__ __launch_bounds__(256) void k_conv(const float* __restrict__ x,
    const float* __restrict__ w0t, const float* __restrict__ b0,
    const u16* __restrict__ w1b, const float* __restrict__ b1,
    const u16* __restrict__ w2b, const float* __restrict__ b2,
    float* __restrict__ h0, float* __restrict__ stat1p){
  int w = threadIdx.x >> 6, lane = threadIdx.x & 63;
  int tid = threadIdx.x;
  int nl = w >> 1, u = w & 1;          // node slot, wave-within-node
  int n = blockIdx.x*2 + nl;
  __shared__ __align__(16) u16 a0t_s[2][36*A0T_STR];  // 5184 B/node; c1 overlays
  __shared__ __align__(16) u16 a1k_s[2][208];
  __shared__ float hstat[2][128];
  u16* a0t = a0t_s[nl];
  u16* a1k = a1k_s[nl];

  const float* xrow = x + (size_t)__builtin_amdgcn_readfirstlane(n)*160;
  float w0r[7];
  #pragma unroll
  for (int k = 0; k < 7; k++) w0r[k] = w0t[k*64 + lane];
  float b0f = b0[lane];

  // zero halo rows: u0 -> rows 0,1 ; u1 -> rows 24..35
  if (u == 0){
    a0t[0*A0T_STR + lane] = 0;
    a0t[1*A0T_STR + lane] = 0;
  } else {
    #pragma unroll
    for (int rp = 24; rp < 36; rp++) a0t[rp*A0T_STR + lane] = 0;
  }

  // conv0 (K=7) + relu + maxpool7 : positions split u0: qp 0..5, u1: qp 6..10
  {
    int qp0 = u ? 6 : 0, qpn = u ? 11 : 6;
    #pragma unroll 2
    for (int qp = qp0; qp < qpn; qp++){
      float win[20];
      #pragma unroll
      for (int j = 0; j < 20; j++) win[j] = xrow[14*qp + j];
      float m0, m1;
      #pragma unroll
      for (int r = 0; r < 7; r++){
        float s = w0r[0]*win[r];
        #pragma unroll
        for (int k = 1; k < 7; k++) s += w0r[k]*win[r+k];
        m0 = r ? fmaxf(m0, s) : s;
      }
      #pragma unroll
      for (int r = 7; r < 14; r++){
        float s = w0r[0]*win[r];
        #pragma unroll
        for (int k = 1; k < 7; k++) s += w0r[k]*win[r+k];
        m1 = (r > 7) ? fmaxf(m1, s) : s;
      }
      a0t[(2 + 2*qp)*A0T_STR + lane] = f2bf(fmaxf(m0 + b0f, 0.f));
      a0t[(3 + 2*qp)*A0T_STR + lane] = f2bf(fmaxf(m1 + b0f, 0.f));
    }
  }
  __syncthreads();   // a0t complete (both waves)

  // conv1 MFMA: wave u owns f-rows [32u, 32u+32) -> mt in {2u, 2u+1}
  int q = lane >> 4, r16 = lane & 15;
  float4v acc[2][2];
  #pragma unroll
  for (int mi = 0; mi < 2; mi++)
    #pragma unroll
    for (int nt = 0; nt < 2; nt++)
      acc[mi][nt] = (float4v){0.f,0.f,0.f,0.f};
  #pragma unroll 1
  for (int ks = 0; ks < 10; ks++){
    int kk = ks >> 1;
    int cbase = (ks & 1)*32 + q*8;
    bf16x8 af[2];
    #pragma unroll
    for (int mi = 0; mi < 2; mi++)
      af[mi] = *(const bf16x8*)(w1b + (16*(2*u + mi) + r16)*320 + ks*32 + q*8);
    bf16x8 bv[2];
    #pragma unroll
    for (int nt = 0; nt < 2; nt++)
      bv[nt] = *(const bf16x8*)(a0t + (r16 + 16*nt + kk)*A0T_STR + cbase);
    #pragma unroll
    for (int mi = 0; mi < 2; mi++)
      #pragma unroll
      for (int nt = 0; nt < 2; nt++)
        acc[mi][nt] = __builtin_amdgcn_mfma_f32_16x16x32_bf16(af[mi], bv[nt], acc[mi][nt], 0, 0, 0);
  }
  __syncthreads();   // all a0t reads complete before c1 overlay

  // bias + relu -> c1 (bf16, overlays a0t)
  u16* c1 = a0t;
  #pragma unroll
  for (int mi = 0; mi < 2; mi++){
    int mt = 2*u + mi;
    float4 bb = *(const float4*)(b1 + 16*mt + 4*q);
    #pragma unroll
    for (int reg = 0; reg < 4; reg++){
      int m = 16*mt + q*4 + reg;
      float bv_ = ((const float*)&bb)[reg];
      c1[m*C1_STR + r16] = f2bf(fmaxf(acc[mi][0][reg] + bv_, 0.f));
      if (r16 <= 4)
        c1[m*C1_STR + 16 + r16] = f2bf(fmaxf(acc[mi][1][reg] + bv_, 0.f));
    }
  }
  __syncthreads();   // c1 complete

  // maxpool7 (21 -> 3): both waves compute all 64 channels (identical writes, benign)
  {
    bf16x8 f0 = *(const bf16x8*)(c1 + lane*C1_STR);
    bf16x8 f1 = *(const bf16x8*)(c1 + lane*C1_STR + 8);
    bf16x8 f2 = *(const bf16x8*)(c1 + lane*C1_STR + 16);
    float v[24];
    #pragma unroll
    for (int j = 0; j < 8; j++){
      v[j]    = bf2f((u16)f0[j]);
      v[8+j]  = bf2f((u16)f1[j]);
      v[16+j] = bf2f((u16)f2[j]);
    }
    #pragma unroll
    for (int t = 0; t < 3; t++){
      float m = v[t*7];
      #pragma unroll
      for (int r = 1; r < 7; r++) m = fmaxf(m, v[t*7+r]);
      a1k[lane*3 + t] = f2bf(m);
    }
  }

  // conv2 via MFMA: wave u does mt {2u, 2u+1} (own-wave a1k writes suffice)
  float4v acc2[2];
  #pragma unroll
  for (int mi = 0; mi < 2; mi++) acc2[mi] = (float4v){0.f,0.f,0.f,0.f};
  #pragma unroll
  for (int ks = 0; ks < 6; ks++){
    bf16x8 bs = *(const bf16x8*)(a1k + ks*32 + q*8);
    #pragma unroll
    for (int mi = 0; mi < 2; mi++){
      bf16x8 af = *(const bf16x8*)(w2b + (16*(2*u + mi) + r16)*192 + ks*32 + q*8);
      acc2[mi] = __builtin_amdgcn_mfma_f32_16x16x32_bf16(af, bs, acc2[mi], 0, 0, 0);
    }
  }
  if (r16 == 0){
    #pragma unroll
    for (int mi = 0; mi < 2; mi++)
      #pragma unroll
      for (int reg = 0; reg < 4; reg++){
        int f = 16*(2*u + mi) + 4*q + reg;
        float v = acc2[mi][reg] + b2[f];
        h0[(size_t)n*64 + f] = v;
        hstat[nl][f] = v;
        hstat[nl][64 + f] = v*v;
      }
  }
  __syncthreads();
  // per-block bn1 partial (2 nodes) -> 32-way bucketed atomics
  if (tid < 128){
    float s = hstat[0][tid] + hstat[1][tid];
    atomicAdd(&stat1p[(blockIdx.x & 31)*128 + tid], s);
  }
}

// ---------------- fused GNN: edge-tanh head + 3 MFMA layers + bn2 partials --
#define EW_STR 72
#define HS_STR 136
#define HWT_STR 72
__global__ __launch_bounds__(512) void k_gnn(const float* __restrict__ h0,
    const float* __restrict__ stat1p,
    const float* __restrict__ bn1g, const float* __restrict__ bn1b,
    const u16* __restrict__ gwt0, const float* __restrict__ gb0,
    const u16* __restrict__ gwt1, const float* __restrict__ gb1,
    const u16* __restrict__ gwt2, const float* __restrict__ gb2,
    const float* __restrict__ ef, const float* __restrict__ eww,
    const float* __restrict__ ewb, float* __restrict__ out2,
    u16* __restrict__ hB, float* __restrict__ stat2p){
  int g = blockIdx.x, tid = threadIdx.x;
  int w = tid >> 6, lane = tid & 63, q = lane >> 4, r16 = lane & 15;
  int dt = w & 3, jh = w >> 2;
  __shared__ u16 hs[64*HS_STR];
  __shared__ u16 hwT[128*HWT_STR];
  __shared__ u16 ewl[64*EW_STR];
  __shared__ float bsc[64], bsh[64];
  __shared__ float st2[256];

  bf16x8 af0[2], af1[4], af2[4];
  #pragma unroll
  for (int ks = 0; ks < 2; ks++)
    af0[ks] = *(const bf16x8*)(gwt0 + (16*w + r16)*64 + ks*32 + q*8);
  #pragma unroll
  for (int ks = 0; ks < 4; ks++)
    af1[ks] = *(const bf16x8*)(gwt1 + (16*w + r16)*128 + ks*32 + q*8);
  #pragma unroll
  for (int ks = 0; ks < 4; ks++)
    af2[ks] = *(const bf16x8*)(gwt2 + (16*w + r16)*128 + ks*32 + q*8);
  float4 b40 = *(const float4*)(gb0 + 16*w + 4*q);
  float4 b41 = *(const float4*)(gb1 + 16*w + 4*q);
  float4 b42 = *(const float4*)(gb2 + 16*w + 4*q);

  if (tid < 64){
    float s = 0.f, s2 = 0.f;
    #pragma unroll
    for (int r = 0; r < 32; r++){
      s  += stat1p[r*128 + tid];
      s2 += stat1p[r*128 + 64 + tid];
    }
    float m = s*(1.f/NNODES), v = s2*(1.f/NNODES) - m*m;
    float sc = rsqrtf(v + 1e-5f)*bn1g[tid];
    bsc[tid] = sc; bsh[tid] = bn1b[tid] - m*sc;
  }
  if (tid < 256) st2[tid] = 0.f;
  {
    unsigned* td = (unsigned*)ewl;
    for (int idx = tid; idx < 64*EW_STR/2; idx += 512) td[idx] = 0;
  }
  {
    unsigned* hsd = (unsigned*)hs;
    for (int idx = tid; idx < 3*(HS_STR/2); idx += 512){
      int rr = 61 + idx/(HS_STR/2), cc = idx%(HS_STR/2);
      hsd[rr*(HS_STR/2) + cc] = 0;
    }
  }
  __syncthreads();

  {
    float v0 = eww[0], v1 = eww[1], v2 = eww[2], bb = ewb[0];
    const float* efg = ef + (size_t)g*EPG*3;
    for (int idx = tid; idx < EPG; idx += 512){
      const float* p = efg + idx*3;
      float v = tanhf(p[0]*v0 + p[1]*v1 + p[2]*v2 + bb);
      int s = idx/60, r = idx - s*60;
      int d = r + (r >= s ? 1 : 0);
      ewl[d*EW_STR + s] = f2bf(v);
      out2[(size_t)idx*128 + g] = v;
    }
  }
  {
    unsigned* hsd = (unsigned*)hs;
    for (int idx = tid; idx < 61*32; idx += 512){
      int i = idx >> 5, kw = idx & 31;
      float2 hv = *(const float2*)(h0 + ((size_t)g*61 + i)*64 + kw*2);
      int k0 = kw*2;
      float a = hv.x*bsc[k0] + bsh[k0];
      float b = hv.y*bsc[k0+1] + bsh[k0+1];
      hsd[i*(HS_STR/2) + kw] = (unsigned)f2bf(a) | ((unsigned)f2bf(b) << 16);
    }
  }
  __syncthreads();
  bf16x8 ewf[2];
  #pragma unroll
  for (int ks = 0; ks < 2; ks++)
    ewf[ks] = *(const bf16x8*)(ewl + (16*dt + r16)*EW_STR + ks*32 + q*8);

  // layer 0
  #pragma unroll
  for (int nt = 0; nt < 4; nt++){
    float4v acc = {b40.x, b40.y, b40.z, b40.w};
    #pragma unroll
    for (int ks = 0; ks < 2; ks++){
      bf16x8 bv = *(const bf16x8*)(hs + (nt*16 + r16)*HS_STR + ks*32 + q*8);
      acc = __builtin_amdgcn_mfma_f32_16x16x32_bf16(af0[ks], bv, acc, 0, 0, 0);
    }
    #pragma unroll
    for (int r = 0; r < 4; r++)
      hwT[(16*w + 4*q + r)*HWT_STR + nt*16 + r16] = f2bf(acc[r]);
  }
  __syncthreads();
  #pragma unroll
  for (int nt = 0; nt < 4; nt++){
    int j = (jh*4 + nt)*16;
    float4v acc = {0.f,0.f,0.f,0.f};
    #pragma unroll
    for (int ks = 0; ks < 2; ks++){
      bf16x8 bv = *(const bf16x8*)(hwT + (j + r16)*HWT_STR + ks*32 + q*8);
      acc = __builtin_amdgcn_mfma_f32_16x16x32_bf16(ewf[ks], bv, acc, 0, 0, 0);
    }
    #pragma unroll
    for (int r = 0; r < 4; r++){
      int d = 16*dt + 4*q + r;
      hs[d*HS_STR + j + r16] = f2bf(fmaxf(acc[r], 0.f));
    }
  }
  __syncthreads();

  // layer 1
  #pragma unroll
  for (int nt = 0; nt < 4; nt++){
    float4v acc = {b41.x, b41.y, b41.z, b41.w};
    #pragma unroll
    for (int ks = 0; ks < 4; ks++){
      bf16x8 bv = *(const bf16x8*)(hs + (nt*16 + r16)*HS_STR + ks*32 + q*8);
      acc = __builtin_amdgcn_mfma_f32_16x16x32_bf16(af1[ks], bv, acc, 0, 0, 0);
    }
    #pragma unroll
    for (int r = 0; r < 4; r++)
      hwT[(16*w + 4*q + r)*HWT_STR + nt*16 + r16] = f2bf(acc[r]);
  }
  __syncthreads();
  #pragma unroll
  for (int nt = 0; nt < 4; nt++){
    int j = (jh*4 + nt)*16;
    float4v acc = {0.f,0.f,0.f,0.f};
    #pragma unroll
    for (int ks = 0; ks < 2; ks++){
      bf16x8 bv = *(const bf16x8*)(hwT + (j + r16)*HWT_STR + ks*32 + q*8);
      acc = __builtin_amdgcn_mfma_f32_16x16x32_bf16(ewf[ks], bv, acc, 0, 0, 0);
    }
    #pragma unroll
    for (int r = 0; r < 4; r++){
      int d = 16*dt + 4*q + r;
      hs[d*HS_STR + j + r16] = f2bf(fmaxf(acc[r], 0.f));
    }
  }
  __syncthreads();

  // layer 2 (+ bn2 partial tail, atomic-free global)
  #pragma unroll
  for (int nt = 0; nt < 4; nt++){
    float4v acc = {b42.x, b42.y, b42.z, b42.w};
    #pragma unroll
    for (int ks = 0; ks < 4; ks++){
      bf16x8 bv = *(const bf16x8*)(hs + (nt*16 + r16)*HS_STR + ks*32 + q*8);
      acc = __builtin_amdgcn_mfma_f32_16x16x32_bf16(af2[ks], bv, acc, 0, 0, 0);
    }
    #pragma unroll
    for (int r = 0; r < 4; r++)
      hwT[(16*w + 4*q + r)*HWT_STR + nt*16 + r16] = f2bf(acc[r]);
  }
  __syncthreads();
  #pragma unroll
  for (int nt = 0; nt < 4; nt++){
    int j = (jh*4 + nt)*16;
    float4v acc = {0.f,0.f,0.f,0.f};
    #pragma unroll
    for (int ks = 0; ks < 2; ks++){
      bf16x8 bv = *(const bf16x8*)(hwT + (j + r16)*HWT_STR + ks*32 + q*8);
      acc = __builtin_amdgcn_mfma_f32_16x16x32_bf16(ewf[ks], bv, acc, 0, 0, 0);
    }
    float cs = 0.f, cq = 0.f;
    #pragma unroll
    for (int r = 0; r < 4; r++){
      int d = 16*dt + 4*q + r;
      if (d < 61){
        float v = acc[r];
        hB[((size_t)g*61 + d)*128 + j + r16] = f2bf(v);
        cs += v; cq += v*v;
      }
    }
    int col = j + r16;
    atomicAdd(&st2[col], cs);
    atomicAdd(&st2[128 + col], cq);
  }
  __syncthreads();
  if (tid < 256) stat2p[(size_t)tid*128 + g] = st2[tid];
}

// ---------------- lin0 via MFMA, atomic split-K into y0pre ------------------
#define AS_STR 136
__global__ __launch_bounds__(256) void k_mlp0(const u16* __restrict__ hB,
    const float* __restrict__ stat2p,
    const float* __restrict__ bn2g, const float* __restrict__ bn2b,
    const u16* __restrict__ lw0t, float* __restrict__ y0pre){
  int bi = blockIdx.x; int i = bi >> 2, sub = bi & 3;
  int oh = sub & 1, gh = sub >> 1;
  int tid = threadIdx.x, w = tid >> 6, lane = tid & 63, q = lane >> 4, r16 = lane & 15;
  __shared__ u16 As[64*AS_STR];
  __shared__ float sc2[128], sh2[128];
  if (tid < 128){
    float4v sa = {0,0,0,0}, sb = {0,0,0,0};
    #pragma unroll
    for (int r = 0; r < 32; r++){
      sa += *(const float4v*)(stat2p + (size_t)tid*128 + r*4);
      sb += *(const float4v*)(stat2p + (size_t)(128 + tid)*128 + r*4);
    }
    float s = sa[0]+sa[1]+sa[2]+sa[3], s2 = sb[0]+sb[1]+sb[2]+sb[3];
    float m = s*(1.f/NNODES), v = s2*(1.f/NNODES) - m*m;
    float sc = rsqrtf(v + 1e-5f)*bn2g[tid];
    sc2[tid] = sc; sh2[tid] = bn2b[tid] - m*sc;
  }
  __syncthreads();
  {
    const unsigned* hbd = (const unsigned*)hB;
    unsigned* asd = (unsigned*)As;
    for (int idx = tid; idx < 4096; idx += 256){
      int gg = gh*64 + (idx >> 6), kw = idx & 63;
      unsigned pv = hbd[((size_t)gg*61 + i)*64 + kw];
      int k0 = kw*2;
      float a = bf2f(pv & 0xffffu)*sc2[k0] + sh2[k0];
      float b = bf2f(pv >> 16)*sc2[k0+1] + sh2[k0+1];
      asd[(idx >> 6)*(AS_STR/2) + kw] = (unsigned)f2bf(a) | ((unsigned)f2bf(b) << 16);
    }
  }
  __syncthreads();
  const u16* wbase = lw0t + ((size_t)i*128 + oh*64)*128;
  bf16x8 af[4];
  #pragma unroll
  for (int ks = 0; ks < 4; ks++)
    af[ks] = *(const bf16x8*)(As + (16*w + r16)*AS_STR + ks*32 + q*8);
  #pragma unroll
  for (int nt = 0; nt < 4; nt++){
    float4v acc = {0.f,0.f,0.f,0.f};
    #pragma unroll
    for (int ks = 0; ks < 4; ks++){
      bf16x8 bv = *(const bf16x8*)(wbase + (size_t)(nt*16 + r16)*128 + ks*32 + q*8);
      acc = __builtin_amdgcn_mfma_f32_16x16x32_bf16(af[ks], bv, acc, 0, 0, 0);
    }
    #pragma unroll
    for (int r = 0; r < 4; r++){
      int g = gh*64 + 16*w + 4*q + r;
      atomicAdd(&y0pre[(size_t)g*128 + oh*64 + nt*16 + r16], acc[r]);
    }
  }
}

// ---------------- epilogue: bias+relu + lin1 + lin2 + log_softmax -----------
__global__ __launch_bounds__(128) void k_mlp1(const float* __restrict__ y0pre,
    const float* __restrict__ lb0, const float* __restrict__ W1,
    const float* __restrict__ lb1, const float* __restrict__ W2,
    const float* __restrict__ lb2, float* __restrict__ out){
  int g = blockIdx.x, o = threadIdx.x;
  __shared__ float y0[128], y1[128], red[128];
  y0[o] = fmaxf(y0pre[(size_t)g*128 + o] + lb0[o], 0.f);
  __syncthreads();
  float a = lb1[o];
  #pragma unroll 8
  for (int k = 0; k < 128; k++) a += y0[k]*W1[k*128 + o];
  y1[o] = fmaxf(a, 0.f);
  __syncthreads();
  int c = o & 3, kb = o >> 2;
  float a2 = 0.f;
  #pragma unroll
  for (int j = 0; j < 4; j++){
    int k = kb + 32*j;
    a2 += y1[k]*W2[k*4 + c];
  }
  red[o] = a2;
  __syncthreads();
  #pragma unroll
  for (int off = 64; off >= 4; off >>= 1){
    if (o < off) red[o] += red[o + off];
    __syncthreads();
  }
  if (o == 0){
    float v0 = red[0]+lb2[0], v1 = red[1]+lb2[1], v2 = red[2]+lb2[2], v3 = red[3]+lb2[3];
    float m = fmaxf(fmaxf(v0,v1), fmaxf(v2,v3));
    float lse = m + logf(expf(v0-m)+expf(v1-m)+expf(v2-m)+expf(v3-m));
    out[g*4+0]=v0-lse; out[g*4+1]=v1-lse; out[g*4+2]=v2-lse; out[g*4+3]=v3-lse;
  }
}

extern "C" void kernel_launch(void* const* d_in, const int* in_sizes, int n_in,
                              void* d_out, int out_size, void* d_ws, size_t ws_size,
                              hipStream_t stream){
  const float* x    = (const float*)d_in[0];
  const float* ef   = (const float*)d_in[3];
  const float* cw0  = (const float*)d_in[4];
  const float* cb0  = (const float*)d_in[5];
  const float* cw1  = (const float*)d_in[6];
  const float* cb1  = (const float*)d_in[7];
  const float* cw2  = (const float*)d_in[8];
  const float* cb2  = (const float*)d_in[9];
  const float* bn1g = (const float*)d_in[10];
  const float* bn1b = (const float*)d_in[11];
  const float* gw0  = (const float*)d_in[12];
  const float* gb0  = (const float*)d_in[13];
  const float* gw1  = (const float*)d_in[14];
  const float* gb1  = (const float*)d_in[15];
  const float* gw2  = (const float*)d_in[16];
  const float* gb2  = (const float*)d_in[17];
  const float* bn2g = (const float*)d_in[18];
  const float* bn2b = (const float*)d_in[19];
  const float* lw0  = (const float*)d_in[20];
  const float* lb0  = (const float*)d_in[21];
  const float* lw1  = (const float*)d_in[22];
  const float* lb1  = (const float*)d_in[23];
  const float* lw2  = (const float*)d_in[24];
  const float* lb2  = (const float*)d_in[25];
  const float* eww  = (const float*)d_in[26];
  const float* ewb  = (const float*)d_in[27];
  float* out = (float*)d_out;

  float* ws   = (float*)d_ws;
  float* w1s  = ws;               // 10240 f
  float* w2s  = w1s + 10240;      // 6144 f
  float* w0t  = w2s + 6144;       // 448 f
  float* gws0 = w0t + 448;        // 4096 f
  float* gws1 = gws0 + 4096;      // 8192 f
  float* gws2 = gws1 + 8192;      // 8192 f
  float* h0   = gws2 + 8192;      // 499712 f (7808*64 f32)
  float* hBs  = h0 + 499712;      // 499712 f (7808*128 u16)
  float* lw0s = hBs + 499712;     // 499712 f (61*128*128 u16)
  float* accs = lw0s + 499712;    // stat1p(4096) | y0pre(16384) | stat2p(32768)

  u16* w1b    = (u16*)w1s;
  u16* w2b    = (u16*)w2s;
  u16* gwt0   = (u16*)gws0;
  u16* gwt1   = (u16*)gws1;
  u16* gwt2   = (u16*)gws2;
  u16* hB     = (u16*)hBs;
  u16* lw0t   = (u16*)lw0s;
  float* stat1p = accs;           // 32 buckets x 128
  float* y0pre  = accs + 4096;    // 128 x 128
  float* stat2p = accs + 20480;   // 256 cols x 128 graphs

  hipMemsetAsync(accs, 0, 20480*sizeof(float), stream);   // stat1p + y0pre
  k_prep <<<534, 256, 0, stream>>>(cw0, cw1, cw2, gw0, gw1, gw2, lw0,
                                   w0t, w1b, w2b, gwt0, gwt1, gwt2, lw0t);
  k_conv <<<NNODES/2, 256, 0, stream>>>(x, w0t, cb0, w1b, cb1, w2b, cb2, h0, stat1p);
  k_gnn  <<<NGRAPH, 512, 0, stream>>>(h0, stat1p, bn1g, bn1b,
                                      gwt0, gb0, gwt1, gb1, gwt2, gb2,
                                      ef, eww, ewb, out + 512, hB, stat2p);
  k_mlp0 <<<NPGN*4, 256, 0, stream>>>(hB, stat2p, bn2g, bn2b, lw0t, y0pre);
  k_mlp1 <<<NGRAPH, 128, 0, stream>>>(y0pre, lb0, lw1, lb1, lw2, lb2, out);
}

// Round 15
// 227.701 us; speedup vs baseline: 1.7738x; 1.0335x over previous
//
#include <hip/hip_runtime.h>
#include <math.h>

#define NPGN 61
#define NGRAPH 128
#define NNODES (NPGN*NGRAPH)   // 7808
#define EPG 3660               // 61*60 edges per graph

typedef float float4v __attribute__((ext_vector_type(4)));
typedef short bf16x8 __attribute__((ext_vector_type(8)));
typedef unsigned short u16;

__device__ __forceinline__ u16 f2bf(float v){
  union { float f; unsigned u; } x; x.f = v;
  unsigned r = (x.u + 0x7FFFu + ((x.u >> 16) & 1u)) >> 16;
  return (u16)r;
}
__device__ __forceinline__ float bf2f(unsigned u){
  union { unsigned u; float f; } x; x.u = u << 16;
  return x.f;
}

// ---------------- fused prep: weight re-layouts + lw0 transpose -------------
__global__ __launch_bounds__(256) void k_prep(const float* __restrict__ w0,
    const float* __restrict__ w1, const float* __restrict__ w2,
    const float* __restrict__ gw0, const float* __restrict__ gw1, const float* __restrict__ gw2,
    const float* __restrict__ lw0,
    float* __restrict__ w0t, u16* __restrict__ w1b, u16* __restrict__ w2b,
    u16* __restrict__ gwt0, u16* __restrict__ gwt1, u16* __restrict__ gwt2,
    u16* __restrict__ lw0t){
  __shared__ __align__(16) u16 tile[32*132];
  int b = blockIdx.x, tid = threadIdx.x;
  if (b < 290){
    int idx = b*256 + tid;
    if (idx < 20480){
      int f = idx / 320, r = idx - f*320;
      int kk = r >> 6, c = r & 63;
      w1b[idx] = f2bf(w1[f*320 + c*5 + kk]);
    } else if (idx < 32768){
      int j = idx - 20480; w2b[j] = f2bf(w2[j]);
    } else if (idx < 40960){
      int j = idx - 32768; int jj = j >> 6, k = j & 63; gwt0[j] = f2bf(gw0[k*128 + jj]);
    } else if (idx < 57344){
      int j = idx - 40960; int jj = j >> 7, k = j & 127; gwt1[j] = f2bf(gw1[k*128 + jj]);
    } else if (idx < 73728){
      int j = idx - 57344; int jj = j >> 7, k = j & 127; gwt2[j] = f2bf(gw2[k*128 + jj]);
    } else if (idx < 74176){
      int j = idx - 73728; int k = j >> 6, f = j & 63; w0t[j] = w0[f*7 + k];
    }
  } else {
    int bb = b - 290;
    int i = bb >> 2, oq = bb & 3;      // o-chunk of 32
    for (int idx = tid; idx < 4096; idx += 256){
      int k = idx >> 5, ol = idx & 31;
      tile[ol*132 + k] = f2bf(lw0[((size_t)i*128 + k)*128 + oq*32 + ol]);
    }
    __syncthreads();
    unsigned* dst = (unsigned*)lw0t;
    for (int idx = tid; idx < 2048; idx += 256){
      int ol = idx >> 6, kw = idx & 63;
      unsigned v = (unsigned)tile[ol*132 + 2*kw] | ((unsigned)tile[ol*132 + 2*kw + 1] << 16);
      dst[((size_t)i*128 + oq*32 + ol)*64 + kw] = v;
    }
  }
}

// ---------------- fused conv stack + bucketed bn1-stats tail ----------------
// 4 independent waves/block, 1 node/wave; conv0 scalar-VALU, conv1/conv2 MFMA
#define A0T_STR 72   // u16 units (144 B)
#define C1_STR 40    // u16 units (80 B)
__global__ __launch_bounds__(256) void k_conv(const float* __restrict__ x,
    const float* __restrict__ w0t, const float* __restrict__ b0,
    const u16* __restrict__ w1b, const float* __restrict__ b1,
    const u16* __restrict__ w2b, const float* __restrict__ b2,
    float* __restrict__ h0, float* __restrict__ stat1p){
  int w = threadIdx.x >> 6, lane = threadIdx.x & 63;
  int tid = threadIdx.x;
  int n = blockIdx.x*4 + w;
  __shared__ __align__(16) u16 a0t_s[4][36*A0T_STR];  // 5184 B/wave; c1 overlays
  __shared__ __align__(16) u16 a1k_s[4][208];         // conv2 input vector
  __shared__ float hstat[4][128];
  u16* a0t = a0t_s[w];
  u16* a1k = a1k_s[w];

  // wave-uniform x row -> scalar loads
  const float* xrow = x + (size_t)__builtin_amdgcn_readfirstlane(n)*160;

  float w0r[7];
  #pragma unroll
  for (int k = 0; k < 7; k++) w0r[k] = w0t[k*64 + lane];
  float b0f = b0[lane];
  #pragma unroll
  for (int rp = 0; rp < 36; rp++)
    if (rp < 2 || rp >= 24) a0t[rp*A0T_STR + lane] = 0;

  // conv0 (K=7) + relu + maxpool7 : 160 -> 154 -> 22 ; lane = channel
  #pragma unroll 2
  for (int qp = 0; qp < 11; qp++){
    float win[20];
    #pragma unroll
    for (int j = 0; j < 20; j++) win[j] = xrow[14*qp + j];
    float m0, m1;
    #pragma unroll
    for (int r = 0; r < 7; r++){
      float s = w0r[0]*win[r];
      #pragma unroll
      for (int k = 1; k < 7; k++) s += w0r[k]*win[r+k];
      m0 = r ? fmaxf(m0, s) : s;
    }
    #pragma unroll
    for (int r = 7; r < 14; r++){
      float s = w0r[0]*win[r];
      #pragma unroll
      for (int k = 1; k < 7; k++) s += w0r[k]*win[r+k];
      m1 = (r > 7) ? fmaxf(m1, s) : s;
    }
    a0t[(2 + 2*qp)*A0T_STR + lane] = f2bf(fmaxf(m0 + b0f, 0.f));
    a0t[(3 + 2*qp)*A0T_STR + lane] = f2bf(fmaxf(m1 + b0f, 0.f));
  }

  // conv1 MFMA: C[64f][22p] = W[64f][320] * B[320][22p], k = kk*64 + c
  int q = lane >> 4, r16 = lane & 15;
  float4v acc[4][2];
  #pragma unroll
  for (int mt = 0; mt < 4; mt++)
    #pragma unroll
    for (int nt = 0; nt < 2; nt++)
      acc[mt][nt] = (float4v){0.f,0.f,0.f,0.f};
  #pragma unroll 1
  for (int ks = 0; ks < 10; ks++){
    int kk = ks >> 1;
    int cbase = (ks & 1)*32 + q*8;
    bf16x8 af[4];
    #pragma unroll
    for (int mt = 0; mt < 4; mt++)
      af[mt] = *(const bf16x8*)(w1b + (16*mt + r16)*320 + ks*32 + q*8);
    bf16x8 bv[2];
    #pragma unroll
    for (int nt = 0; nt < 2; nt++)
      bv[nt] = *(const bf16x8*)(a0t + (r16 + 16*nt + kk)*A0T_STR + cbase);
    #pragma unroll
    for (int mt = 0; mt < 4; mt++)
      #pragma unroll
      for (int nt = 0; nt < 2; nt++)
        acc[mt][nt] = __builtin_amdgcn_mfma_f32_16x16x32_bf16(af[mt], bv[nt], acc[mt][nt], 0, 0, 0);
  }

  // bias + relu -> c1 (bf16, overlays a0t; same-wave DS ops in-order)
  u16* c1 = a0t;
  #pragma unroll
  for (int mt = 0; mt < 4; mt++){
    float4 bb = *(const float4*)(b1 + 16*mt + 4*q);
    #pragma unroll
    for (int reg = 0; reg < 4; reg++){
      int m = 16*mt + q*4 + reg;
      float bv_ = ((const float*)&bb)[reg];
      c1[m*C1_STR + r16] = f2bf(fmaxf(acc[mt][0][reg] + bv_, 0.f));
      if (r16 <= 4)
        c1[m*C1_STR + 16 + r16] = f2bf(fmaxf(acc[mt][1][reg] + bv_, 0.f));
    }
  }

  // maxpool7 (21 -> 3), lane = channel; contiguous k-vector a1k[c*3+t]
  {
    bf16x8 f0 = *(const bf16x8*)(c1 + lane*C1_STR);
    bf16x8 f1 = *(const bf16x8*)(c1 + lane*C1_STR + 8);
    bf16x8 f2 = *(const bf16x8*)(c1 + lane*C1_STR + 16);
    float v[24];
    #pragma unroll
    for (int j = 0; j < 8; j++){
      v[j]    = bf2f((u16)f0[j]);
      v[8+j]  = bf2f((u16)f1[j]);
      v[16+j] = bf2f((u16)f2[j]);
    }
    #pragma unroll
    for (int t = 0; t < 3; t++){
      float m = v[t*7];
      #pragma unroll
      for (int r = 1; r < 7; r++) m = fmaxf(m, v[t*7+r]);
      a1k[lane*3 + t] = f2bf(m);
    }
  }

  // conv2 via MFMA: C[f][*] = W2[64f][192k] * a1[192k]
  float4v acc2[4];
  #pragma unroll
  for (int mt = 0; mt < 4; mt++) acc2[mt] = (float4v){0.f,0.f,0.f,0.f};
  #pragma unroll
  for (int ks = 0; ks < 6; ks++){
    bf16x8 bs = *(const bf16x8*)(a1k + ks*32 + q*8);
    #pragma unroll
    for (int mt = 0; mt < 4; mt++){
      bf16x8 af = *(const bf16x8*)(w2b + (16*mt + r16)*192 + ks*32 + q*8);
      acc2[mt] = __builtin_amdgcn_mfma_f32_16x16x32_bf16(af, bs, acc2[mt], 0, 0, 0);
    }
  }
  if (r16 == 0){
    #pragma unroll
    for (int mt = 0; mt < 4; mt++)
      #pragma unroll
      for (int reg = 0; reg < 4; reg++){
        int f = 16*mt + 4*q + reg;
        float v = acc2[mt][reg] + b2[f];
        h0[(size_t)n*64 + f] = v;
        hstat[w][f] = v;
        hstat[w][64 + f] = v*v;
      }
  }
  __syncthreads();
  // per-block bn1 partial -> 32-way bucketed atomic accumulators (low contention)
  if (tid < 128){
    float a = hstat[0][tid] + hstat[1][tid] + hstat[2][tid] + hstat[3][tid];
    atomicAdd(&stat1p[(blockIdx.x & 31)*128 + tid], a);
  }
}

// ---------------- fused GNN: edge-tanh head + 3 MFMA layers + bn2 partials --
#define EW_STR 72
#define HS_STR 136
#define HWT_STR 72
__global__ __launch_bounds__(512) void k_gnn(const float* __restrict__ h0,
    const float* __restrict__ stat1p,
    const float* __restrict__ bn1g, const float* __restrict__ bn1b,
    const u16* __restrict__ gwt0, const float* __restrict__ gb0,
    const u16* __restrict__ gwt1, const float* __restrict__ gb1,
    const u16* __restrict__ gwt2, const float* __restrict__ gb2,
    const float* __restrict__ ef, const float* __restrict__ eww,
    const float* __restrict__ ewb, float* __restrict__ out2,
    u16* __restrict__ hB, float* __restrict__ stat2p){
  int g = blockIdx.x, tid = threadIdx.x;
  int w = tid >> 6, lane = tid & 63, q = lane >> 4, r16 = lane & 15;
  int dt = w & 3, jh = w >> 2;
  __shared__ u16 hs[64*HS_STR];
  __shared__ u16 hwT[128*HWT_STR];
  __shared__ u16 ewl[64*EW_STR];
  __shared__ float bsc[64], bsh[64];
  __shared__ float st2[256];

  bf16x8 af0[2], af1[4], af2[4];
  #pragma unroll
  for (int ks = 0; ks < 2; ks++)
    af0[ks] = *(const bf16x8*)(gwt0 + (16*w + r16)*64 + ks*32 + q*8);
  #pragma unroll
  for (int ks = 0; ks < 4; ks++)
    af1[ks] = *(const bf16x8*)(gwt1 + (16*w + r16)*128 + ks*32 + q*8);
  #pragma unroll
  for (int ks = 0; ks < 4; ks++)
    af2[ks] = *(const bf16x8*)(gwt2 + (16*w + r16)*128 + ks*32 + q*8);
  float4 b40 = *(const float4*)(gb0 + 16*w + 4*q);
  float4 b41 = *(const float4*)(gb1 + 16*w + 4*q);
  float4 b42 = *(const float4*)(gb2 + 16*w + 4*q);

  // bn1 scale/shift from bucketed accumulators
  if (tid < 64){
    float s = 0.f, s2 = 0.f;
    #pragma unroll
    for (int r = 0; r < 32; r++){
      s  += stat1p[r*128 + tid];
      s2 += stat1p[r*128 + 64 + tid];
    }
    float m = s*(1.f/NNODES), v = s2*(1.f/NNODES) - m*m;
    float sc = rsqrtf(v + 1e-5f)*bn1g[tid];
    bsc[tid] = sc; bsh[tid] = bn1b[tid] - m*sc;
  }
  if (tid < 256) st2[tid] = 0.f;
  {
    unsigned* td = (unsigned*)ewl;
    for (int idx = tid; idx < 64*EW_STR/2; idx += 512) td[idx] = 0;
  }
  {
    unsigned* hsd = (unsigned*)hs;
    for (int idx = tid; idx < 3*(HS_STR/2); idx += 512){
      int rr = 61 + idx/(HS_STR/2), cc = idx%(HS_STR/2);
      hsd[rr*(HS_STR/2) + cc] = 0;
    }
  }
  __syncthreads();

  // edge tanh -> dense LDS matrix + transposed global output
  {
    float v0 = eww[0], v1 = eww[1], v2 = eww[2], bb = ewb[0];
    const float* efg = ef + (size_t)g*EPG*3;
    for (int idx = tid; idx < EPG; idx += 512){
      const float* p = efg + idx*3;
      float v = tanhf(p[0]*v0 + p[1]*v1 + p[2]*v2 + bb);
      int s = idx/60, r = idx - s*60;
      int d = r + (r >= s ? 1 : 0);
      ewl[d*EW_STR + s] = f2bf(v);
      out2[(size_t)idx*128 + g] = v;
    }
  }
  // bn1-normalized node features -> hs
  {
    unsigned* hsd = (unsigned*)hs;
    for (int idx = tid; idx < 61*32; idx += 512){
      int i = idx >> 5, kw = idx & 31;
      float2 hv = *(const float2*)(h0 + ((size_t)g*61 + i)*64 + kw*2);
      int k0 = kw*2;
      float a = hv.x*bsc[k0] + bsh[k0];
      float b = hv.y*bsc[k0+1] + bsh[k0+1];
      hsd[i*(HS_STR/2) + kw] = (unsigned)f2bf(a) | ((unsigned)f2bf(b) << 16);
    }
  }
  __syncthreads();
  bf16x8 ewf[2];
  #pragma unroll
  for (int ks = 0; ks < 2; ks++)
    ewf[ks] = *(const bf16x8*)(ewl + (16*dt + r16)*EW_STR + ks*32 + q*8);

  // layer 0
  #pragma unroll
  for (int nt = 0; nt < 4; nt++){
    float4v acc = {b40.x, b40.y, b40.z, b40.w};
    #pragma unroll
    for (int ks = 0; ks < 2; ks++){
      bf16x8 bv = *(const bf16x8*)(hs + (nt*16 + r16)*HS_STR + ks*32 + q*8);
      acc = __builtin_amdgcn_mfma_f32_16x16x32_bf16(af0[ks], bv, acc, 0, 0, 0);
    }
    #pragma unroll
    for (int r = 0; r < 4; r++)
      hwT[(16*w + 4*q + r)*HWT_STR + nt*16 + r16] = f2bf(acc[r]);
  }
  __syncthreads();
  #pragma unroll
  for (int nt = 0; nt < 4; nt++){
    int j = (jh*4 + nt)*16;
    float4v acc = {0.f,0.f,0.f,0.f};
    #pragma unroll
    for (int ks = 0; ks < 2; ks++){
      bf16x8 bv = *(const bf16x8*)(hwT + (j + r16)*HWT_STR + ks*32 + q*8);
      acc = __builtin_amdgcn_mfma_f32_16x16x32_bf16(ewf[ks], bv, acc, 0, 0, 0);
    }
    #pragma unroll
    for (int r = 0; r < 4; r++){
      int d = 16*dt + 4*q + r;
      hs[d*HS_STR + j + r16] = f2bf(fmaxf(acc[r], 0.f));
    }
  }
  __syncthreads();

  // layer 1
  #pragma unroll
  for (int nt = 0; nt < 4; nt++){
    float4v acc = {b41.x, b41.y, b41.z, b41.w};
    #pragma unroll
    for (int ks = 0; ks < 4; ks++){
      bf16x8 bv = *(const bf16x8*)(hs + (nt*16 + r16)*HS_STR + ks*32 + q*8);
      acc = __builtin_amdgcn_mfma_f32_16x16x32_bf16(af1[ks], bv, acc, 0, 0, 0);
    }
    #pragma unroll
    for (int r = 0; r < 4; r++)
      hwT[(16*w + 4*q + r)*HWT_STR + nt*16 + r16] = f2bf(acc[r]);
  }
  __syncthreads();
  #pragma unroll
  for (int nt = 0; nt < 4; nt++){
    int j = (jh*4 + nt)*16;
    float4v acc = {0.f,0.f,0.f,0.f};
    #pragma unroll
    for (int ks = 0; ks < 2; ks++){
      bf16x8 bv = *(const bf16x8*)(hwT + (j + r16)*HWT_STR + ks*32 + q*8);
      acc = __builtin_amdgcn_mfma_f32_16x16x32_bf16(ewf[ks], bv, acc, 0, 0, 0);
    }
    #pragma unroll
    for (int r = 0; r < 4; r++){
      int d = 16*dt + 4*q + r;
      hs[d*HS_STR + j + r16] = f2bf(fmaxf(acc[r], 0.f));
    }
  }
  __syncthreads();

  // layer 2 (+ bn2 partial tail, atomic-free)
  #pragma unroll
  for (int nt = 0; nt < 4; nt++){
    float4v acc = {b42.x, b42.y, b42.z, b42.w};
    #pragma unroll
    for (int ks = 0; ks < 4; ks++){
      bf16x8 bv = *(const bf16x8*)(hs + (nt*16 + r16)*HS_STR + ks*32 + q*8);
      acc = __builtin_amdgcn_mfma_f32_16x16x32_bf16(af2[ks], bv, acc, 0, 0, 0);
    }
    #pragma unroll
    for (int r = 0; r < 4; r++)
      hwT[(16*w + 4*q + r)*HWT_STR + nt*16 + r16] = f2bf(acc[r]);
  }
  __syncthreads();
  #pragma unroll
  for (int nt = 0; nt < 4; nt++){
    int j = (jh*4 + nt)*16;
    float4v acc = {0.f,0.f,0.f,0.f};
    #pragma unroll
    for (int ks = 0; ks < 2; ks++){
      bf16x8 bv = *(const bf16x8*)(hwT + (j + r16)*HWT_STR + ks*32 + q*8);
      acc = __builtin_amdgcn_mfma_f32_16x16x32_bf16(ewf[ks], bv, acc, 0, 0, 0);
    }
    float cs = 0.f, cq = 0.f;
    #pragma unroll
    for (int r = 0; r < 4; r++){
      int d = 16*dt + 4*q + r;
      if (d < 61){
        float v = acc[r];
        hB[((size_t)g*61 + d)*128 + j + r16] = f2bf(v);
        cs += v; cq += v*v;
      }
    }
    int col = j + r16;
    atomicAdd(&st2[col], cs);       // LDS atomics (block-local, cheap)
    atomicAdd(&st2[128 + col], cq);
  }
  __syncthreads();
  if (tid < 256) stat2p[(size_t)tid*128 + g] = st2[tid];   // private column, no atomics
}

// ---------------- lin0 via MFMA, atomic split-K into y0pre ------------------
#define AS_STR 136
__global__ __launch_bounds__(256) void k_mlp0(const u16* __restrict__ hB,
    const float* __restrict__ stat2p,
    const float* __restrict__ bn2g, const float* __restrict__ bn2b,
    const u16* __restrict__ lw0t, float* __restrict__ y0pre){
  int bi = blockIdx.x; int i = bi >> 2, sub = bi & 3;
  int oh = sub & 1, gh = sub >> 1;
  int tid = threadIdx.x, w = tid >> 6, lane = tid & 63, q = lane >> 4, r16 = lane & 15;
  __shared__ u16 As[64*AS_STR];
  __shared__ float sc2[128], sh2[128];
  if (tid < 128){
    float4v sa = {0,0,0,0}, sb = {0,0,0,0};
    #pragma unroll
    for (int r = 0; r < 32; r++){
      sa += *(const float4v*)(stat2p + (size_t)tid*128 + r*4);
      sb += *(const float4v*)(stat2p + (size_t)(128 + tid)*128 + r*4);
    }
    float s = sa[0]+sa[1]+sa[2]+sa[3], s2 = sb[0]+sb[1]+sb[2]+sb[3];
    float m = s*(1.f/NNODES), v = s2*(1.f/NNODES) - m*m;
    float sc = rsqrtf(v + 1e-5f)*bn2g[tid];
    sc2[tid] = sc; sh2[tid] = bn2b[tid] - m*sc;
  }
  __syncthreads();
  {
    const unsigned* hbd = (const unsigned*)hB;
    unsigned* asd = (unsigned*)As;
    for (int idx = tid; idx < 4096; idx += 256){
      int gg = gh*64 + (idx >> 6), kw = idx & 63;
      unsigned pv = hbd[((size_t)gg*61 + i)*64 + kw];
      int k0 = kw*2;
      float a = bf2f(pv & 0xffffu)*sc2[k0] + sh2[k0];
      float b = bf2f(pv >> 16)*sc2[k0+1] + sh2[k0+1];
      asd[(idx >> 6)*(AS_STR/2) + kw] = (unsigned)f2bf(a) | ((unsigned)f2bf(b) << 16);
    }
  }
  __syncthreads();
  const u16* wbase = lw0t + ((size_t)i*128 + oh*64)*128;
  bf16x8 af[4];
  #pragma unroll
  for (int ks = 0; ks < 4; ks++)
    af[ks] = *(const bf16x8*)(As + (16*w + r16)*AS_STR + ks*32 + q*8);
  #pragma unroll
  for (int nt = 0; nt < 4; nt++){
    float4v acc = {0.f,0.f,0.f,0.f};
    #pragma unroll
    for (int ks = 0; ks < 4; ks++){
      bf16x8 bv = *(const bf16x8*)(wbase + (size_t)(nt*16 + r16)*128 + ks*32 + q*8);
      acc = __builtin_amdgcn_mfma_f32_16x16x32_bf16(af[ks], bv, acc, 0, 0, 0);
    }
    #pragma unroll
    for (int r = 0; r < 4; r++){
      int g = gh*64 + 16*w + 4*q + r;
      atomicAdd(&y0pre[(size_t)g*128 + oh*64 + nt*16 + r16], acc[r]);
    }
  }
}

// ---------------- epilogue: bias+relu + lin1 + lin2 + log_softmax -----------
__global__ __launch_bounds__(128) void k_mlp1(const float* __restrict__ y0pre,
    const float* __restrict__ lb0, const float* __restrict__ W1,
    const float* __restrict__ lb1, const float* __restrict__ W2,
    const float* __restrict__ lb2, float* __restrict__ out){
  int g = blockIdx.x, o = threadIdx.x;
  __shared__ float y0[128], y1[128], red[128];
  y0[o] = fmaxf(y0pre[(size_t)g*128 + o] + lb0[o], 0.f);
  __syncthreads();
  float a = lb1[o];
  #pragma unroll 8
  for (int k = 0; k < 128; k++) a += y0[k]*W1[k*128 + o];
  y1[o] = fmaxf(a, 0.f);
  __syncthreads();
  int c = o & 3, kb = o >> 2;
  float a2 = 0.f;
  #pragma unroll
  for (int j = 0; j < 4; j++){
    int k = kb + 32*j;
    a2 += y1[k]*W2[k*4 + c];
  }
  red[o] = a2;
  __syncthreads();
  #pragma unroll
  for (int off = 64; off >= 4; off >>= 1){
    if (o < off) red[o] += red[o + off];
    __syncthreads();
  }
  if (o == 0){
    float v0 = red[0]+lb2[0], v1 = red[1]+lb2[1], v2 = red[2]+lb2[2], v3 = red[3]+lb2[3];
    float m = fmaxf(fmaxf(v0,v1), fmaxf(v2,v3));
    float lse = m + logf(expf(v0-m)+expf(v1-m)+expf(v2-m)+expf(v3-m));
    out[g*4+0]=v0-lse; out[g*4+1]=v1-lse; out[g*4+2]=v2-lse; out[g*4+3]=v3-lse;
  }
}

extern "C" void kernel_launch(void* const* d_in, const int* in_sizes, int n_in,
                              void* d_out, int out_size, void* d_ws, size_t ws_size,
                              hipStream_t stream){
  const float* x    = (const float*)d_in[0];
  const float* ef   = (const float*)d_in[3];
  const float* cw0  = (const float*)d_in[4];
  const float* cb0  = (const float*)d_in[5];
  const float* cw1  = (const float*)d_in[6];
  const float* cb1  = (const float*)d_in[7];
  const float* cw2  = (const float*)d_in[8];
  const float* cb2  = (const float*)d_in[9];
  const float* bn1g = (const float*)d_in[10];
  const float* bn1b = (const float*)d_in[11];
  const float* gw0  = (const float*)d_in[12];
  const float* gb0  = (const float*)d_in[13];
  const float* gw1  = (const float*)d_in[14];
  const float* gb1  = (const float*)d_in[15];
  const float* gw2  = (const float*)d_in[16];
  const float* gb2  = (const float*)d_in[17];
  const float* bn2g = (const float*)d_in[18];
  const float* bn2b = (const float*)d_in[19];
  const float* lw0  = (const float*)d_in[20];
  const float* lb0  = (const float*)d_in[21];
  const float* lw1  = (const float*)d_in[22];
  const float* lb1  = (const float*)d_in[23];
  const float* lw2  = (const float*)d_in[24];
  const float* lb2  = (const float*)d_in[25];
  const float* eww  = (const float*)d_in[26];
  const float* ewb  = (const float*)d_in[27];
  float* out = (float*)d_out;

  float* ws   = (float*)d_ws;
  float* w1s  = ws;               // 10240 f
  float* w2s  = w1s + 10240;      // 6144 f
  float* w0t  = w2s + 6144;       // 448 f
  float* gws0 = w0t + 448;        // 4096 f
  float* gws1 = gws0 + 4096;      // 8192 f
  float* gws2 = gws1 + 8192;      // 8192 f
  float* h0   = gws2 + 8192;      // 499712 f (7808*64 f32)
  float* hBs  = h0 + 499712;      // 499712 f (7808*128 u16)
  float* lw0s = hBs + 499712;     // 499712 f (61*128*128 u16)
  float* accs = lw0s + 499712;    // stat1p(4096) | y0pre(16384) | stat2p(32768)

  u16* w1b    = (u16*)w1s;
  u16* w2b    = (u16*)w2s;
  u16* gwt0   = (u16*)gws0;
  u16* gwt1   = (u16*)gws1;
  u16* gwt2   = (u16*)gws2;
  u16* hB     = (u16*)hBs;
  u16* lw0t   = (u16*)lw0s;
  float* stat1p = accs;           // 32 buckets x 128
  float* y0pre  = accs + 4096;    // 128 x 128
  float* stat2p = accs + 20480;   // 256 cols x 128 graphs

  hipMemsetAsync(accs, 0, 20480*sizeof(float), stream);   // stat1p + y0pre
  k_prep <<<534, 256, 0, stream>>>(cw0, cw1, cw2, gw0, gw1, gw2, lw0,
                                   w0t, w1b, w2b, gwt0, gwt1, gwt2, lw0t);
  k_conv <<<NNODES/4, 256, 0, stream>>>(x, w0t, cb0, w1b, cb1, w2b, cb2, h0, stat1p);
  k_gnn  <<<NGRAPH, 512, 0, stream>>>(h0, stat1p, bn1g, bn1b,
                                      gwt0, gb0, gwt1, gb1, gwt2, gb2,
                                      ef, eww, ewb, out + 512, hB, stat2p);
  k_mlp0 <<<NPGN*4, 256, 0, stream>>>(hB, stat2p, bn2g, bn2b, lw0t, y0pre);
  k_mlp1 <<<NGRAPH, 128, 0, stream>>>(y0pre, lb0, lw1, lb1, lw2, lb2, out);
}